// Round 7
// baseline (182.134 us; speedup 1.0000x reference)
//
#include <hip/hip_runtime.h>
#include <stdint.h>

#define TT 16
#define BB 16
#define CC 256
#define HS 31
#define HT 15
#define OUTW 17
#define NCH 13                      // channels (flattened b,t,c) per block
#define NCHAN (BB*TT*CC)            // 65536
#define CORR_ELEMS ((size_t)NCHAN*OUTW*OUTW)
#define SROW 17                     // dwords per s_e row (16 data + 1 pad)
#define SOFF 527                    // s_e dwords per channel (31*17)
#define WROW 16                     // dwords per w row (15 used)
#define CHTOT 767                   // 527 + 240 dwords per channel (odd -> bank spread)

typedef _Float16 h2_t __attribute__((ext_vector_type(2)));

__device__ __forceinline__ unsigned packh2(float a, float b) {
    return __builtin_bit_cast(unsigned, __builtin_amdgcn_cvt_pkrtz(a, b));
}
__device__ __forceinline__ h2_t ash2(unsigned u) {
    return __builtin_bit_cast(h2_t, u);
}

// logical channel ch = (b*T + t)*C + c  ->  s_f index (t*B + b)*C + c
__device__ __forceinline__ int s_index(int ch) {
    int bt = ch >> 8, c = ch & 255;
    int b = bt >> 4, t = bt & 15;
    return (t * BB + b) * CC + c;
}

__global__ __launch_bounds__(256, 4)
void corr_kernel(const float* __restrict__ s_f, const float* __restrict__ t_f,
                 float* __restrict__ corr)
{
    // per channel: s_e rows (17 dwords x 31) then w_dup rows (16 dwords x 15)
    __shared__ unsigned lds[NCH * CHTOT];   // 39884 B -> 4 blocks/CU

    const int tid = threadIdx.x;
    const int ch_base = blockIdx.x * NCH;

    // ---- stage s: pack (s[y][2j], s[y][2j+1]) -> dword j of row y ----
    {
        const int jcol = tid & 15;          // pair-column 0..15
        const int r0   = tid >> 4;          // row 0..15
        const int x0   = 2 * jcol;
        const bool hasb  = (jcol < 15);     // x=31 doesn't exist -> pad 0
        const int  r1    = r0 + 16;
        const bool hasr1 = (r1 <= 30);
#pragma unroll
        for (int j = 0; j < NCH; ++j) {
            int ch = ch_base + j; if (ch >= NCHAN) ch = NCHAN - 1;
            const float* src = s_f + (size_t)s_index(ch) * (HS * HS);
            unsigned* sdst = lds + j * CHTOT;
            float a0 = src[r0 * HS + x0];
            float b0 = hasb ? src[r0 * HS + x0 + 1] : 0.0f;
            sdst[r0 * SROW + jcol] = packh2(a0, b0);
            if (hasr1) {
                float a1 = src[r1 * HS + x0];
                float b1 = hasb ? src[r1 * HS + x0 + 1] : 0.0f;
                sdst[r1 * SROW + jcol] = packh2(a1, b1);
            }
        }
    }

    // ---- stage w duplicated pairs: wd[ky][kx] = (w, w) ----
    for (int idx = tid; idx < NCH * HT * WROW; idx += 256) {   // 3120
        int j  = idx / (HT * WROW);
        int e  = idx - j * (HT * WROW);
        int ky = e >> 4, kx = e & 15;
        if (kx < HT) {
            int ch = ch_base + j; if (ch >= NCHAN) ch = NCHAN - 1;
            int bt = ch >> 8, c = ch & 255, b = bt >> 4;
            float w = t_f[(size_t)(b * CC + c) * (HT * HT) + ky * HT + kx];
            lds[j * CHTOT + SOFF + e] = packh2(w, w);
        }
    }

    __syncthreads();

    // ---- compute: thread = (c_sub, oy); acc2[m] = (out[2m], out[2m+1]) ----
    const int c_sub = tid / OUTW;
    const int oy    = tid - c_sub * OUTW;
    if (c_sub >= NCH) return;
    const int ch = ch_base + c_sub;
    if (ch >= NCHAN) return;

    const unsigned* se = lds + c_sub * CHTOT + oy * SROW;
    const unsigned* wd = lds + c_sub * CHTOT + SOFF;

    h2_t acc2[9];
#pragma unroll
    for (int m = 0; m < 9; ++m) acc2[m] = ash2(0u);

#pragma unroll 1
    for (int ky = 0; ky < HT; ++ky) {
        // even pairs of row y=oy+ky: sp[j] = (s[2j], s[2j+1]); dword offsets fit read2 imm
        unsigned sp[16];
#pragma unroll
        for (int u = 0; u < 16; ++u) sp[u] = se[ky * SROW + u];
        // odd pairs: so_[j] = (s[2j+1], s[2j+2])
        unsigned so_[15];
#pragma unroll
        for (int u = 0; u < 15; ++u)
            so_[u] = __builtin_amdgcn_alignbit(sp[u + 1], sp[u], 16);
        // w duplicated pairs (broadcast within channel group)
        unsigned wr_[15];
#pragma unroll
        for (int k = 0; k < 15; ++k) wr_[k] = wd[ky * WROW + k];

#pragma unroll
        for (int kx = 0; kx < 15; ++kx) {
            const unsigned* sr = (kx & 1) ? so_ : sp;   // kx compile-time (unrolled)
            const int q = kx >> 1;
            h2_t wv = ash2(wr_[kx]);
#pragma unroll
            for (int m = 0; m < 9; ++m)
                acc2[m] = __builtin_elementwise_fma(ash2(sr[q + m]), wv, acc2[m]);
        }
    }

    float* outp = corr + (size_t)ch * (OUTW * OUTW) + (size_t)oy * OUTW;
#pragma unroll
    for (int m = 0; m < 8; ++m) {
        outp[2 * m]     = (float)acc2[m][0];
        outp[2 * m + 1] = (float)acc2[m][1];
    }
    outp[16] = (float)acc2[8][0];
}

__global__ void masks_kernel(const float* __restrict__ corr,
                             const int* __restrict__ pos,
                             float* __restrict__ masks)
{
    int gid = blockIdx.x * 256 + threadIdx.x;   // flattened (b*T+t)*C + c
    if (gid >= NCHAN) return;
    int bt = gid >> 8;
    int b  = bt >> 4;
    int t  = bt & 15;
    int p0 = pos[(b * TT + t) * 2 + 0];
    int p1 = pos[(b * TT + t) * 2 + 1];
    masks[gid] = corr[(size_t)gid * (OUTW * OUTW) + p0 * OUTW + p1];
}

extern "C" void kernel_launch(void* const* d_in, const int* in_sizes, int n_in,
                              void* d_out, int out_size, void* d_ws, size_t ws_size,
                              hipStream_t stream)
{
    const float* s_f = (const float*)d_in[0];
    const float* t_f = (const float*)d_in[1];
    const int*   pos = (const int*)d_in[2];
    float* corr  = (float*)d_out;
    float* masks = corr + CORR_ELEMS;

    int nblocks = (NCHAN + NCH - 1) / NCH;   // 5042
    corr_kernel<<<nblocks, 256, 0, stream>>>(s_f, t_f, corr);
    masks_kernel<<<NCHAN / 256, 256, 0, stream>>>(corr, pos, masks);
}

// Round 8
// 166.457 us; speedup vs baseline: 1.0942x; 1.0942x over previous
//
#include <hip/hip_runtime.h>
#include <stdint.h>

#define TT 16
#define BB 16
#define CC 256
#define HS 31
#define HT 15
#define OUTW 17
#define NCH 15                      // channels per block
#define NCHAN (BB*TT*CC)            // 65536
#define CORR_ELEMS ((size_t)NCHAN*OUTW*OUTW)
#define SROW 20                     // dwords per s row (16 data + 4 pad; pad holds w)
#define SCH  620                    // dwords per channel (31*20); w row ky in pads of rows 2ky,2ky+1

typedef _Float16 h2_t __attribute__((ext_vector_type(2)));

__device__ __forceinline__ unsigned packh2(float a, float b) {
    return __builtin_bit_cast(unsigned, __builtin_amdgcn_cvt_pkrtz(a, b));
}
__device__ __forceinline__ float fdot2f(unsigned a, unsigned b, float c) {
    return __builtin_amdgcn_fdot2(__builtin_bit_cast(h2_t, a),
                                  __builtin_bit_cast(h2_t, b), c, false);
}

// logical channel ch = (b*T + t)*C + c  ->  s_f index (t*B + b)*C + c
__device__ __forceinline__ int s_index(int ch) {
    int bt = ch >> 8, c = ch & 255;
    int b = bt >> 4, t = bt & 15;
    return (t * BB + b) * CC + c;
}

__global__ __launch_bounds__(256, 4)
void corr_kernel(const float* __restrict__ s_f, const float* __restrict__ t_f,
                 const int* __restrict__ pos,
                 float* __restrict__ corr, float* __restrict__ masks)
{
    __shared__ unsigned lds[NCH * SCH];   // 37200 B -> 4 blocks/CU

    const int tid = threadIdx.x;
    const int ch_base = blockIdx.x * NCH;

    // ---- stage s: pack (s[y][2j], s[y][2j+1]) -> dword j of row y (dwords 0..15) ----
    {
        const int jcol = tid & 15;
        const int r0   = tid >> 4;          // 0..15
        const int x0   = 2 * jcol;
        const bool hasb  = (jcol < 15);
        const int  r1    = r0 + 16;
        const bool hasr1 = (r1 <= 30);
#pragma unroll
        for (int j = 0; j < NCH; ++j) {
            int ch = ch_base + j; if (ch >= NCHAN) ch = NCHAN - 1;
            const float* src = s_f + (size_t)s_index(ch) * (HS * HS);
            float a0 = src[r0 * HS + x0];
            float b0 = hasb ? src[r0 * HS + x0 + 1] : 0.0f;
            lds[j * SCH + r0 * SROW + jcol] = packh2(a0, b0);
            if (hasr1) {
                float a1 = src[r1 * HS + x0];
                float b1 = hasb ? src[r1 * HS + x0 + 1] : 0.0f;
                lds[j * SCH + r1 * SROW + jcol] = packh2(a1, b1);
            }
        }
    }

    // ---- stage w into the row pads: w row ky (8 pair-dwords) at 40ky+16..19, 40ky+36..39 ----
    for (int idx = tid; idx < NCH * HT * 8; idx += 256) {   // 1800
        int j  = idx / (HT * 8);
        int e  = idx - j * (HT * 8);
        int ky = e >> 3, p = e & 7;
        int ch = ch_base + j; if (ch >= NCHAN) ch = NCHAN - 1;
        int bt = ch >> 8, c = ch & 255, b = bt >> 4;
        const float* wsrc = t_f + (size_t)(b * CC + c) * (HT * HT) + ky * HT;
        float a  = wsrc[2 * p];
        float bb = (p < 7) ? wsrc[2 * p + 1] : 0.0f;
        int off = j * SCH + 40 * ky + 16 + ((p & 4) ? 20 + (p & 3) : (p & 3));
        lds[off] = packh2(a, bb);
    }

    __syncthreads();

    // ---- compute: thread = (c_sub, oy) owns one 17-wide output row ----
    const int c_sub = tid / OUTW;
    const int oy    = tid - c_sub * OUTW;
    if (c_sub >= NCH) return;
    const int ch = ch_base + c_sub;
    if (ch >= NCHAN) return;

    const unsigned* chb = lds + c_sub * SCH;

    float acc[OUTW];
#pragma unroll
    for (int m = 0; m < OUTW; ++m) acc[m] = 0.0f;

    uint4 A0, A1, A2, A3, AW0, AW1;
    uint4 B0, B1, B2, B3, BW0, BW1;

#define LOADS(S0,S1,S2,S3,W0,W1,KY) do {                                   \
        const uint4* sr = (const uint4*)(chb + (oy + (KY)) * SROW);        \
        S0 = sr[0]; S1 = sr[1]; S2 = sr[2]; S3 = sr[3];                    \
        W0 = *(const uint4*)(chb + 40 * (KY) + 16);                        \
        W1 = *(const uint4*)(chb + 40 * (KY) + 36);                        \
    } while (0)

#define COMPUTE(S0,S1,S2,S3,W0,W1) do {                                    \
        unsigned sp[16] = {S0.x,S0.y,S0.z,S0.w, S1.x,S1.y,S1.z,S1.w,       \
                           S2.x,S2.y,S2.z,S2.w, S3.x,S3.y,S3.z,S3.w};      \
        unsigned wp[8]  = {W0.x,W0.y,W0.z,W0.w, W1.x,W1.y,W1.z,W1.w};      \
        unsigned so_[15], wo_[8];                                          \
        _Pragma("unroll")                                                  \
        for (int u = 0; u < 15; ++u)                                       \
            so_[u] = __builtin_amdgcn_alignbit(sp[u + 1], sp[u], 16);      \
        wo_[0] = wp[0] << 16;                                              \
        _Pragma("unroll")                                                  \
        for (int r = 1; r < 8; ++r)                                        \
            wo_[r] = __builtin_amdgcn_alignbit(wp[r], wp[r - 1], 16);      \
        _Pragma("unroll")                                                  \
        for (int e = 0; e < 9; ++e)                                        \
            _Pragma("unroll")                                              \
            for (int jj = 0; jj < 8; ++jj)                                 \
                acc[2 * e] = fdot2f(sp[e + jj], wp[jj], acc[2 * e]);       \
        _Pragma("unroll")                                                  \
        for (int o = 0; o < 8; ++o)                                        \
            _Pragma("unroll")                                              \
            for (int r = 0; r < 8; ++r)                                    \
                acc[2 * o + 1] = fdot2f(sp[o + r], wo_[r], acc[2 * o + 1]);\
    } while (0)

    // 2-deep pipeline over ky = 0..14
    LOADS(A0,A1,A2,A3,AW0,AW1, 0);
#pragma unroll 1
    for (int kk = 0; kk < 7; ++kk) {
        LOADS(B0,B1,B2,B3,BW0,BW1, 2 * kk + 1);
        COMPUTE(A0,A1,A2,A3,AW0,AW1);
        LOADS(A0,A1,A2,A3,AW0,AW1, 2 * kk + 2);
        COMPUTE(B0,B1,B2,B3,BW0,BW1);
    }
    COMPUTE(A0,A1,A2,A3,AW0,AW1);   // ky = 14

#undef LOADS
#undef COMPUTE

    // ---- epilogue: corr row + fused masks gather ----
    float* outp = corr + (size_t)ch * (OUTW * OUTW) + (size_t)oy * OUTW;
#pragma unroll
    for (int m = 0; m < OUTW; ++m) outp[m] = acc[m];

    const int bt = ch >> 8;
    const int p0 = pos[2 * bt];
    const int p1 = pos[2 * bt + 1];
    if (oy == p0) {
        float v = acc[0];
#pragma unroll
        for (int m = 1; m < OUTW; ++m) v = (p1 == m) ? acc[m] : v;
        masks[ch] = v;
    }
}

extern "C" void kernel_launch(void* const* d_in, const int* in_sizes, int n_in,
                              void* d_out, int out_size, void* d_ws, size_t ws_size,
                              hipStream_t stream)
{
    const float* s_f = (const float*)d_in[0];
    const float* t_f = (const float*)d_in[1];
    const int*   pos = (const int*)d_in[2];
    float* corr  = (float*)d_out;
    float* masks = corr + CORR_ELEMS;

    int nblocks = (NCHAN + NCH - 1) / NCH;   // 4370
    corr_kernel<<<nblocks, 256, 0, stream>>>(s_f, t_f, pos, corr, masks);
}

// Round 9
// 164.523 us; speedup vs baseline: 1.1070x; 1.0118x over previous
//
#include <hip/hip_runtime.h>
#include <stdint.h>

#define TT 16
#define BB 16
#define CC 256
#define HS 31
#define HT 15
#define OUTW 17
#define NCH 13                      // channels per block
#define NCHAN (BB*TT*CC)            // 65536
#define CORR_ELEMS ((size_t)NCHAN*OUTW*OUTW)
#define SROW 20                     // dwords per s row (16 data + 4 pad; pad holds w)
#define SCH  620                    // dwords per channel; LDS = 13*620*4 = 32240 B -> 5 blocks/CU

typedef _Float16 h2_t __attribute__((ext_vector_type(2)));

__device__ __forceinline__ unsigned packh2(float a, float b) {
    return __builtin_bit_cast(unsigned, __builtin_amdgcn_cvt_pkrtz(a, b));
}
__device__ __forceinline__ float fdot2f(unsigned a, unsigned b, float c) {
    return __builtin_amdgcn_fdot2(__builtin_bit_cast(h2_t, a),
                                  __builtin_bit_cast(h2_t, b), c, false);
}

// logical channel ch = (b*T + t)*C + c  ->  s_f index (t*B + b)*C + c
__device__ __forceinline__ int s_index(int ch) {
    int bt = ch >> 8, c = ch & 255;
    int b = bt >> 4, t = bt & 15;
    return (t * BB + b) * CC + c;
}

__global__ __launch_bounds__(256)
__attribute__((amdgpu_waves_per_eu(5, 5)))
void corr_kernel(const float* __restrict__ s_f, const float* __restrict__ t_f,
                 const int* __restrict__ pos,
                 float* __restrict__ corr, float* __restrict__ masks)
{
    __shared__ unsigned lds[NCH * SCH];   // 32240 B

    const int tid = threadIdx.x;
    const int ch_base = blockIdx.x * NCH;

    // ---- stage s: pack (s[y][2j], s[y][2j+1]) -> dword j of row y (dwords 0..15) ----
    {
        const int jcol = tid & 15;
        const int r0   = tid >> 4;          // 0..15
        const int x0   = 2 * jcol;
        const bool hasb  = (jcol < 15);
        const int  r1    = r0 + 16;
        const bool hasr1 = (r1 <= 30);
#pragma unroll
        for (int j = 0; j < NCH; ++j) {
            int ch = ch_base + j; if (ch >= NCHAN) ch = NCHAN - 1;
            const float* src = s_f + (size_t)s_index(ch) * (HS * HS);
            float a0 = src[r0 * HS + x0];
            float b0 = hasb ? src[r0 * HS + x0 + 1] : 0.0f;
            lds[j * SCH + r0 * SROW + jcol] = packh2(a0, b0);
            if (hasr1) {
                float a1 = src[r1 * HS + x0];
                float b1 = hasb ? src[r1 * HS + x0 + 1] : 0.0f;
                lds[j * SCH + r1 * SROW + jcol] = packh2(a1, b1);
            }
        }
    }

    // ---- stage w into the row pads: w row ky (8 pair-dwords) at 40ky+16..19, 40ky+36..39 ----
    for (int idx = tid; idx < NCH * HT * 8; idx += 256) {   // 1560
        int j  = idx / (HT * 8);
        int e  = idx - j * (HT * 8);
        int ky = e >> 3, p = e & 7;
        int ch = ch_base + j; if (ch >= NCHAN) ch = NCHAN - 1;
        int bt = ch >> 8, c = ch & 255, b = bt >> 4;
        const float* wsrc = t_f + (size_t)(b * CC + c) * (HT * HT) + ky * HT;
        float a  = wsrc[2 * p];
        float bb = (p < 7) ? wsrc[2 * p + 1] : 0.0f;
        int off = j * SCH + 40 * ky + 16 + ((p & 4) ? 20 + (p & 3) : (p & 3));
        lds[off] = packh2(a, bb);
    }

    __syncthreads();

    // ---- compute: thread = (c_sub, oy) owns one 17-wide output row ----
    const int c_sub = tid / OUTW;
    const int oy    = tid - c_sub * OUTW;
    if (c_sub >= NCH) return;
    const int ch = ch_base + c_sub;
    if (ch >= NCHAN) return;

    const unsigned* chb = lds + c_sub * SCH;

    float acc[OUTW];
#pragma unroll
    for (int m = 0; m < OUTW; ++m) acc[m] = 0.0f;

    uint4 A0, A1, A2, A3, AW0, AW1;
    uint4 B0, B1, B2, B3, BW0, BW1;

#define LOADS(S0,S1,S2,S3,W0,W1,KY) do {                                   \
        const uint4* sr = (const uint4*)(chb + (oy + (KY)) * SROW);        \
        S0 = sr[0]; S1 = sr[1]; S2 = sr[2]; S3 = sr[3];                    \
        W0 = *(const uint4*)(chb + 40 * (KY) + 16);                        \
        W1 = *(const uint4*)(chb + 40 * (KY) + 36);                        \
    } while (0)

#define COMPUTE(S0,S1,S2,S3,W0,W1) do {                                    \
        unsigned sp[16] = {S0.x,S0.y,S0.z,S0.w, S1.x,S1.y,S1.z,S1.w,       \
                           S2.x,S2.y,S2.z,S2.w, S3.x,S3.y,S3.z,S3.w};      \
        unsigned wp[8]  = {W0.x,W0.y,W0.z,W0.w, W1.x,W1.y,W1.z,W1.w};      \
        unsigned so_[15], wo_[8];                                          \
        _Pragma("unroll")                                                  \
        for (int u = 0; u < 15; ++u)                                       \
            so_[u] = __builtin_amdgcn_alignbit(sp[u + 1], sp[u], 16);      \
        wo_[0] = wp[0] << 16;                                              \
        _Pragma("unroll")                                                  \
        for (int r = 1; r < 8; ++r)                                        \
            wo_[r] = __builtin_amdgcn_alignbit(wp[r], wp[r - 1], 16);      \
        _Pragma("unroll")                                                  \
        for (int e = 0; e < 9; ++e)                                        \
            _Pragma("unroll")                                              \
            for (int jj = 0; jj < 8; ++jj)                                 \
                acc[2 * e] = fdot2f(sp[e + jj], wp[jj], acc[2 * e]);       \
        _Pragma("unroll")                                                  \
        for (int o = 0; o < 8; ++o)                                        \
            _Pragma("unroll")                                              \
            for (int r = 0; r < 8; ++r)                                    \
                acc[2 * o + 1] = fdot2f(sp[o + r], wo_[r], acc[2 * o + 1]);\
    } while (0)

    // 2-deep pipeline over ky = 0..14
    LOADS(A0,A1,A2,A3,AW0,AW1, 0);
#pragma unroll 1
    for (int kk = 0; kk < 7; ++kk) {
        LOADS(B0,B1,B2,B3,BW0,BW1, 2 * kk + 1);
        COMPUTE(A0,A1,A2,A3,AW0,AW1);
        LOADS(A0,A1,A2,A3,AW0,AW1, 2 * kk + 2);
        COMPUTE(B0,B1,B2,B3,BW0,BW1);
    }
    COMPUTE(A0,A1,A2,A3,AW0,AW1);   // ky = 14

#undef LOADS
#undef COMPUTE

    // ---- epilogue: corr row + fused masks gather ----
    float* outp = corr + (size_t)ch * (OUTW * OUTW) + (size_t)oy * OUTW;
#pragma unroll
    for (int m = 0; m < OUTW; ++m) outp[m] = acc[m];

    const int bt = ch >> 8;
    const int p0 = pos[2 * bt];
    const int p1 = pos[2 * bt + 1];
    if (oy == p0) {
        float v = acc[0];
#pragma unroll
        for (int m = 1; m < OUTW; ++m) v = (p1 == m) ? acc[m] : v;
        masks[ch] = v;
    }
}

extern "C" void kernel_launch(void* const* d_in, const int* in_sizes, int n_in,
                              void* d_out, int out_size, void* d_ws, size_t ws_size,
                              hipStream_t stream)
{
    const float* s_f = (const float*)d_in[0];
    const float* t_f = (const float*)d_in[1];
    const int*   pos = (const int*)d_in[2];
    float* corr  = (float*)d_out;
    float* masks = corr + CORR_ELEMS;

    int nblocks = (NCHAN + NCH - 1) / NCH;   // 5042
    corr_kernel<<<nblocks, 256, 0, stream>>>(s_f, t_f, pos, corr, masks);
}

// Round 10
// 127.279 us; speedup vs baseline: 1.4310x; 1.2926x over previous
//
#include <hip/hip_runtime.h>
#include <stdint.h>

#define TT 16
#define BB 16
#define CC 256
#define HS 31
#define HT 15
#define OUTW 17
#define NCH 13                      // channels per block
#define NCHAN (BB*TT*CC)            // 65536
#define CORR_ELEMS ((size_t)NCHAN*OUTW*OUTW)
#define SROW 20                     // dwords per s row (16 data + 4 pad; pad holds w)
#define SCH  620                    // dwords per channel; LDS = 13*620*4 = 32240 B -> 5 blocks/CU

typedef _Float16 h2_t __attribute__((ext_vector_type(2)));

__device__ __forceinline__ unsigned packh2(float a, float b) {
    return __builtin_bit_cast(unsigned, __builtin_amdgcn_cvt_pkrtz(a, b));
}
__device__ __forceinline__ float fdot2f(unsigned a, unsigned b, float c) {
    return __builtin_amdgcn_fdot2(__builtin_bit_cast(h2_t, a),
                                  __builtin_bit_cast(h2_t, b), c, false);
}

// logical channel ch = (b*T + t)*C + c  ->  s_f index (t*B + b)*C + c
__device__ __forceinline__ int s_index(int ch) {
    int bt = ch >> 8, c = ch & 255;
    int b = bt >> 4, t = bt & 15;
    return (t * BB + b) * CC + c;
}

__global__ __launch_bounds__(256, 1)
void corr_kernel(const float* __restrict__ s_f, const float* __restrict__ t_f,
                 const int* __restrict__ pos,
                 float* __restrict__ corr, float* __restrict__ masks)
{
    __shared__ unsigned lds[NCH * SCH];   // 32240 B

    const int tid = threadIdx.x;
    const int ch_base = blockIdx.x * NCH;

    // ---- stage s: issue ALL loads first (fire-and-forget), then pack+write ----
    // thread (r0 = tid>>4, jcol = tid&15) covers rows r0, r0+16, pair-col jcol.
    {
        const int jcol = tid & 15;
        const int r0   = tid >> 4;          // 0..15
        const int x0   = 2 * jcol;
        const bool hasb  = (jcol < 15);     // pair (30,31): x=31 doesn't exist
        const int  r1    = r0 + 16;
        const bool hasr1 = (r1 <= 30);
        // shifted load keeps 8B access in-bounds at row tail
        const int xa = hasb ? x0 : x0 - 1;

        float2 La[NCH], Lb[NCH];
#pragma unroll
        for (int j = 0; j < NCH; ++j) {
            int ch = ch_base + j; if (ch >= NCHAN) ch = NCHAN - 1;
            const float* src = s_f + (size_t)s_index(ch) * (HS * HS);
            La[j] = *(const float2*)(src + r0 * HS + xa);
            Lb[j] = hasr1 ? *(const float2*)(src + r1 * HS + xa)
                          : make_float2(0.f, 0.f);
        }
#pragma unroll
        for (int j = 0; j < NCH; ++j) {
            float a0 = hasb ? La[j].x : La[j].y;
            float b0 = hasb ? La[j].y : 0.0f;
            lds[j * SCH + r0 * SROW + jcol] = packh2(a0, b0);
            if (hasr1) {
                float a1 = hasb ? Lb[j].x : Lb[j].y;
                float b1 = hasb ? Lb[j].y : 0.0f;
                lds[j * SCH + r1 * SROW + jcol] = packh2(a1, b1);
            }
        }
    }

    // ---- stage w into the row pads: w row ky (8 pair-dwords) at 40ky+16..19, 40ky+36..39 ----
    {
        float2 Lw[7];
        int    off[7];
#pragma unroll
        for (int it = 0; it < 7; ++it) {
            int idx = tid + 256 * it;               // < 1560 = NCH*HT*8 for it<7 (tail masked)
            bool ok = idx < NCH * HT * 8;
            int i2  = ok ? idx : 0;
            int j   = i2 / (HT * 8);
            int e   = i2 - j * (HT * 8);
            int ky  = e >> 3, p = e & 7;
            int ch  = ch_base + j; if (ch >= NCHAN) ch = NCHAN - 1;
            int bt = ch >> 8, c = ch & 255, b = bt >> 4;
            const float* wsrc = t_f + (size_t)(b * CC + c) * (HT * HT) + ky * HT;
            int xw = (p < 7) ? 2 * p : 13;          // p==7: load (13,14), keep .y
            Lw[it] = *(const float2*)(wsrc + xw);
            off[it] = ok ? (j * SCH + 40 * ky + 16 + ((p & 4) ? 20 + (p & 3) : (p & 3)))
                         : -1;
            if (p == 7) { Lw[it].x = Lw[it].y; Lw[it].y = 0.0f; }
        }
#pragma unroll
        for (int it = 0; it < 7; ++it)
            if (off[it] >= 0) lds[off[it]] = packh2(Lw[it].x, Lw[it].y);
    }

    __syncthreads();

    // ---- compute: thread = (c_sub, oy) owns one 17-wide output row ----
    const int c_sub = tid / OUTW;
    const int oy    = tid - c_sub * OUTW;
    if (c_sub >= NCH) return;
    const int ch = ch_base + c_sub;
    if (ch >= NCHAN) return;

    const unsigned* chb = lds + c_sub * SCH;

    float acc[OUTW];
#pragma unroll
    for (int m = 0; m < OUTW; ++m) acc[m] = 0.0f;

    uint4 A0, A1, A2, A3, AW0, AW1;
    uint4 B0, B1, B2, B3, BW0, BW1;

#define LOADS(S0,S1,S2,S3,W0,W1,KY) do {                                   \
        const uint4* sr = (const uint4*)(chb + (oy + (KY)) * SROW);        \
        S0 = sr[0]; S1 = sr[1]; S2 = sr[2]; S3 = sr[3];                    \
        W0 = *(const uint4*)(chb + 40 * (KY) + 16);                        \
        W1 = *(const uint4*)(chb + 40 * (KY) + 36);                        \
    } while (0)

#define COMPUTE(S0,S1,S2,S3,W0,W1) do {                                    \
        unsigned sp[16] = {S0.x,S0.y,S0.z,S0.w, S1.x,S1.y,S1.z,S1.w,       \
                           S2.x,S2.y,S2.z,S2.w, S3.x,S3.y,S3.z,S3.w};      \
        unsigned wp[8]  = {W0.x,W0.y,W0.z,W0.w, W1.x,W1.y,W1.z,W1.w};      \
        unsigned so_[15], wo_[8];                                          \
        _Pragma("unroll")                                                  \
        for (int u = 0; u < 15; ++u)                                       \
            so_[u] = __builtin_amdgcn_alignbit(sp[u + 1], sp[u], 16);      \
        wo_[0] = wp[0] << 16;                                              \
        _Pragma("unroll")                                                  \
        for (int r = 1; r < 8; ++r)                                        \
            wo_[r] = __builtin_amdgcn_alignbit(wp[r], wp[r - 1], 16);      \
        _Pragma("unroll")                                                  \
        for (int e = 0; e < 9; ++e)                                        \
            _Pragma("unroll")                                              \
            for (int jj = 0; jj < 8; ++jj)                                 \
                acc[2 * e] = fdot2f(sp[e + jj], wp[jj], acc[2 * e]);       \
        _Pragma("unroll")                                                  \
        for (int o = 0; o < 8; ++o)                                        \
            _Pragma("unroll")                                              \
            for (int r = 0; r < 8; ++r)                                    \
                acc[2 * o + 1] = fdot2f(sp[o + r], wo_[r], acc[2 * o + 1]);\
    } while (0)

    // 2-deep pipeline over ky = 0..14
    LOADS(A0,A1,A2,A3,AW0,AW1, 0);
#pragma unroll 1
    for (int kk = 0; kk < 7; ++kk) {
        LOADS(B0,B1,B2,B3,BW0,BW1, 2 * kk + 1);
        COMPUTE(A0,A1,A2,A3,AW0,AW1);
        LOADS(A0,A1,A2,A3,AW0,AW1, 2 * kk + 2);
        COMPUTE(B0,B1,B2,B3,BW0,BW1);
    }
    COMPUTE(A0,A1,A2,A3,AW0,AW1);   // ky = 14

#undef LOADS
#undef COMPUTE

    // ---- epilogue: corr row + fused masks gather ----
    float* outp = corr + (size_t)ch * (OUTW * OUTW) + (size_t)oy * OUTW;
#pragma unroll
    for (int m = 0; m < OUTW; ++m) outp[m] = acc[m];

    const int bt = ch >> 8;
    const int p0 = pos[2 * bt];
    const int p1 = pos[2 * bt + 1];
    if (oy == p0) {
        float v = acc[0];
#pragma unroll
        for (int m = 1; m < OUTW; ++m) v = (p1 == m) ? acc[m] : v;
        masks[ch] = v;
    }
}

extern "C" void kernel_launch(void* const* d_in, const int* in_sizes, int n_in,
                              void* d_out, int out_size, void* d_ws, size_t ws_size,
                              hipStream_t stream)
{
    const float* s_f = (const float*)d_in[0];
    const float* t_f = (const float*)d_in[1];
    const int*   pos = (const int*)d_in[2];
    float* corr  = (float*)d_out;
    float* masks = corr + CORR_ELEMS;

    int nblocks = (NCHAN + NCH - 1) / NCH;   // 5042
    corr_kernel<<<nblocks, 256, 0, stream>>>(s_f, t_f, pos, corr, masks);
}

// Round 11
// 124.791 us; speedup vs baseline: 1.4595x; 1.0199x over previous
//
#include <hip/hip_runtime.h>
#include <stdint.h>

#define TT 16
#define BB 16
#define CC 256
#define HS 31
#define HT 15
#define OUTW 17
#define NCH 15                      // channels per block; 15*17 = 255/256 lanes active
#define NCHAN (BB*TT*CC)            // 65536
#define CORR_ELEMS ((size_t)NCHAN*OUTW*OUTW)
#define SROW 20                     // dwords per s row (16 data + 4 pad; pad holds w)
#define SCH  620                    // dwords per channel; LDS = 15*620*4 = 37200 B -> 4 blocks/CU

typedef _Float16 h2_t __attribute__((ext_vector_type(2)));

__device__ __forceinline__ unsigned packh2(float a, float b) {
    return __builtin_bit_cast(unsigned, __builtin_amdgcn_cvt_pkrtz(a, b));
}
__device__ __forceinline__ float fdot2f(unsigned a, unsigned b, float c) {
    return __builtin_amdgcn_fdot2(__builtin_bit_cast(h2_t, a),
                                  __builtin_bit_cast(h2_t, b), c, false);
}

// logical channel ch = (b*T + t)*C + c  ->  s_f index (t*B + b)*C + c
__device__ __forceinline__ int s_index(int ch) {
    int bt = ch >> 8, c = ch & 255;
    int b = bt >> 4, t = bt & 15;
    return (t * BB + b) * CC + c;
}

__global__ __launch_bounds__(256, 1)
void corr_kernel(const float* __restrict__ s_f, const float* __restrict__ t_f,
                 const int* __restrict__ pos,
                 float* __restrict__ corr, float* __restrict__ masks)
{
    __shared__ unsigned lds[NCH * SCH];   // 37200 B

    const int tid = threadIdx.x;
    const int ch_base = blockIdx.x * NCH;

    // ---- stage s: issue ALL loads first (fire-and-forget), then pack+write ----
    // thread (r0 = tid>>4, jcol = tid&15) covers rows r0, r0+16, pair-col jcol.
    {
        const int jcol = tid & 15;
        const int r0   = tid >> 4;          // 0..15
        const int x0   = 2 * jcol;
        const bool hasb  = (jcol < 15);     // pair (30,31): x=31 doesn't exist
        const int  r1    = r0 + 16;
        const bool hasr1 = (r1 <= 30);
        // shifted load keeps 8B access in-bounds at row tail
        const int xa = hasb ? x0 : x0 - 1;

        float2 La[NCH], Lb[NCH];
#pragma unroll
        for (int j = 0; j < NCH; ++j) {
            int ch = ch_base + j; if (ch >= NCHAN) ch = NCHAN - 1;
            const float* src = s_f + (size_t)s_index(ch) * (HS * HS);
            La[j] = *(const float2*)(src + r0 * HS + xa);
            Lb[j] = hasr1 ? *(const float2*)(src + r1 * HS + xa)
                          : make_float2(0.f, 0.f);
        }
#pragma unroll
        for (int j = 0; j < NCH; ++j) {
            float a0 = hasb ? La[j].x : La[j].y;
            float b0 = hasb ? La[j].y : 0.0f;
            lds[j * SCH + r0 * SROW + jcol] = packh2(a0, b0);
            if (hasr1) {
                float a1 = hasb ? Lb[j].x : Lb[j].y;
                float b1 = hasb ? Lb[j].y : 0.0f;
                lds[j * SCH + r1 * SROW + jcol] = packh2(a1, b1);
            }
        }
    }

    // ---- stage w into the row pads: w row ky (8 pair-dwords) at 40ky+16..19, 40ky+36..39 ----
    {
        float2 Lw[8];
        int    off[8];
#pragma unroll
        for (int it = 0; it < 8; ++it) {
            int idx = tid + 256 * it;               // < 1800 = NCH*HT*8 (tail masked)
            bool ok = idx < NCH * HT * 8;
            int i2  = ok ? idx : 0;
            int j   = i2 / (HT * 8);
            int e   = i2 - j * (HT * 8);
            int ky  = e >> 3, p = e & 7;
            int ch  = ch_base + j; if (ch >= NCHAN) ch = NCHAN - 1;
            int bt = ch >> 8, c = ch & 255, b = bt >> 4;
            const float* wsrc = t_f + (size_t)(b * CC + c) * (HT * HT) + ky * HT;
            int xw = (p < 7) ? 2 * p : 13;          // p==7: load (13,14), keep .y
            Lw[it] = *(const float2*)(wsrc + xw);
            off[it] = ok ? (j * SCH + 40 * ky + 16 + ((p & 4) ? 20 + (p & 3) : (p & 3)))
                         : -1;
            if (p == 7) { Lw[it].x = Lw[it].y; Lw[it].y = 0.0f; }
        }
#pragma unroll
        for (int it = 0; it < 8; ++it)
            if (off[it] >= 0) lds[off[it]] = packh2(Lw[it].x, Lw[it].y);
    }

    __syncthreads();

    // ---- compute: thread = (c_sub, oy) owns one 17-wide output row ----
    const int c_sub = tid / OUTW;
    const int oy    = tid - c_sub * OUTW;
    if (c_sub >= NCH) return;
    const int ch = ch_base + c_sub;
    if (ch >= NCHAN) return;

    const unsigned* chb = lds + c_sub * SCH;

    float acc[OUTW];
#pragma unroll
    for (int m = 0; m < OUTW; ++m) acc[m] = 0.0f;

    uint4 A0, A1, A2, A3, AW0, AW1;
    uint4 B0, B1, B2, B3, BW0, BW1;

#define LOADS(S0,S1,S2,S3,W0,W1,KY) do {                                   \
        const uint4* sr = (const uint4*)(chb + (oy + (KY)) * SROW);        \
        S0 = sr[0]; S1 = sr[1]; S2 = sr[2]; S3 = sr[3];                    \
        W0 = *(const uint4*)(chb + 40 * (KY) + 16);                        \
        W1 = *(const uint4*)(chb + 40 * (KY) + 36);                        \
    } while (0)

#define COMPUTE(S0,S1,S2,S3,W0,W1) do {                                    \
        unsigned sp[16] = {S0.x,S0.y,S0.z,S0.w, S1.x,S1.y,S1.z,S1.w,       \
                           S2.x,S2.y,S2.z,S2.w, S3.x,S3.y,S3.z,S3.w};      \
        unsigned wp[8]  = {W0.x,W0.y,W0.z,W0.w, W1.x,W1.y,W1.z,W1.w};      \
        unsigned wo_[8];                                                   \
        wo_[0] = wp[0] << 16;                                              \
        _Pragma("unroll")                                                  \
        for (int r = 1; r < 8; ++r)                                        \
            wo_[r] = __builtin_amdgcn_alignbit(wp[r], wp[r - 1], 16);      \
        _Pragma("unroll")                                                  \
        for (int e = 0; e < 9; ++e)                                        \
            _Pragma("unroll")                                              \
            for (int jj = 0; jj < 8; ++jj)                                 \
                acc[2 * e] = fdot2f(sp[e + jj], wp[jj], acc[2 * e]);       \
        _Pragma("unroll")                                                  \
        for (int o = 0; o < 8; ++o)                                        \
            _Pragma("unroll")                                              \
            for (int r = 0; r < 8; ++r)                                    \
                acc[2 * o + 1] = fdot2f(sp[o + r], wo_[r], acc[2 * o + 1]);\
    } while (0)

    // 2-deep pipeline over ky = 0..14
    LOADS(A0,A1,A2,A3,AW0,AW1, 0);
#pragma unroll 1
    for (int kk = 0; kk < 7; ++kk) {
        LOADS(B0,B1,B2,B3,BW0,BW1, 2 * kk + 1);
        COMPUTE(A0,A1,A2,A3,AW0,AW1);
        LOADS(A0,A1,A2,A3,AW0,AW1, 2 * kk + 2);
        COMPUTE(B0,B1,B2,B3,BW0,BW1);
    }
    COMPUTE(A0,A1,A2,A3,AW0,AW1);   // ky = 14

#undef LOADS
#undef COMPUTE

    // ---- epilogue: corr row + fused masks gather ----
    float* outp = corr + (size_t)ch * (OUTW * OUTW) + (size_t)oy * OUTW;
#pragma unroll
    for (int m = 0; m < OUTW; ++m) outp[m] = acc[m];

    const int bt = ch >> 8;
    const int p0 = pos[2 * bt];
    const int p1 = pos[2 * bt + 1];
    if (oy == p0) {
        float v = acc[0];
#pragma unroll
        for (int m = 1; m < OUTW; ++m) v = (p1 == m) ? acc[m] : v;
        masks[ch] = v;
    }
}

extern "C" void kernel_launch(void* const* d_in, const int* in_sizes, int n_in,
                              void* d_out, int out_size, void* d_ws, size_t ws_size,
                              hipStream_t stream)
{
    const float* s_f = (const float*)d_in[0];
    const float* t_f = (const float*)d_in[1];
    const int*   pos = (const int*)d_in[2];
    float* corr  = (float*)d_out;
    float* masks = corr + CORR_ELEMS;

    int nblocks = (NCHAN + NCH - 1) / NCH;   // 4370
    corr_kernel<<<nblocks, 256, 0, stream>>>(s_f, t_f, pos, corr, masks);
}